// Round 10
// baseline (90.737 us; speedup 1.0000x reference)
//
#include <hip/hip_runtime.h>
#include <math.h>

#define S_LEN 2048
#define B_TOT 4096
#define CHUNK 16                  // steps per thread; 128 threads (2 waves) per batch
constexpr float DT       = 1.0f / 200.0f;
constexpr float HALF_DT2 = DT * DT * 0.5f;

// One preintegration step applied to running segment state (R,V,P).
__device__ __forceinline__ void istep(
    float& R00, float& R01, float& R02,
    float& R10, float& R11, float& R12,
    float& R20, float& R21, float& R22,
    float& Vx, float& Vy, float& Vz,
    float& Px, float& Py, float& Pz,
    float wx, float wy, float wz, float ax, float ay, float az)
{
    const float ux = wx * DT, uy = wy * DT, uz = wz * DT;
    const float t2 = ux * ux + uy * uy + uz * uz;          // theta^2 (tiny)
    const float Ac = 1.0f + t2 * (-1.0f / 6.0f  + t2 * (1.0f / 120.0f));
    const float Bc = 0.5f + t2 * (-1.0f / 24.0f + t2 * (1.0f / 720.0f));

    const float K00 = 1.0f + Bc * (ux * ux - t2);
    const float K11 = 1.0f + Bc * (uy * uy - t2);
    const float K22 = 1.0f + Bc * (uz * uz - t2);
    const float bxy = Bc * ux * uy, bxz = Bc * ux * uz, byz = Bc * uy * uz;
    const float aux = Ac * ux, auy = Ac * uy, auz = Ac * uz;
    const float K01 = bxy - auz, K10 = bxy + auz;
    const float K02 = bxz + auy, K20 = bxz - auy;
    const float K12 = byz - aux, K21 = byz + aux;

    float r0, r1, r2;
    r0 = R00 * K00 + R01 * K10 + R02 * K20;
    r1 = R00 * K01 + R01 * K11 + R02 * K21;
    r2 = R00 * K02 + R01 * K12 + R02 * K22;
    R00 = r0; R01 = r1; R02 = r2;
    r0 = R10 * K00 + R11 * K10 + R12 * K20;
    r1 = R10 * K01 + R11 * K11 + R12 * K21;
    r2 = R10 * K02 + R11 * K12 + R12 * K22;
    R10 = r0; R11 = r1; R12 = r2;
    r0 = R20 * K00 + R21 * K10 + R22 * K20;
    r1 = R20 * K01 + R21 * K11 + R22 * K21;
    r2 = R20 * K02 + R21 * K12 + R22 * K22;
    R20 = r0; R21 = r1; R22 = r2;

    const float tx = R00 * ax + R01 * ay + R02 * az;
    const float ty = R10 * ax + R11 * ay + R12 * az;
    const float tz = R20 * ax + R21 * ay + R22 * az;
    Vx += tx * DT; Vy += ty * DT; Vz += tz * DT;
    Px += Vx * DT + tx * HALF_DT2;
    Py += Vy * DT + ty * HALF_DT2;
    Pz += Vz * DT + tz * HALF_DT2;
}

// block = 256 = 4 waves = 2 batches (2 waves/batch); 2048 blocks.
// 4 rounds of 6 float4/lane (4 steps each), wave-cooperative coalesced
// staging (instr m loads slot m*64+lane -> rec=s/6, j=s%6: 96B contiguous
// per record, ~1KB contiguous per wave instruction). LDS record stride 7
// float4 (odd) -> conflict-free b128 reads (2-way/16-lane = free, m136).
// LDS 28.7KB/block -> 5 blocks/CU -> 5 waves/SIMD (vs 3 in R9); prefetch
// one round ahead keeps ~6 loads in flight through ~75% of the body.
// Fences at every LDS write<->read transition (R7 race lesson).
// (256,2): VGPR cap 128 ((256,8) clamps to 32 and spills — R2/R4).
__global__ __launch_bounds__(256, 2)
void preint_kernel(const float* __restrict__ in, float* __restrict__ out)
{
    const int slot = threadIdx.x >> 7;             // batch within block (0..1)
    const int b    = blockIdx.x * 2 + slot;
    const int tid  = threadIdx.x & 127;            // thread within batch = record
    const int lane = threadIdx.x & 63;
    const int half = (threadIdx.x >> 6) & 1;       // which wave of the batch
    const int wv   = threadIdx.x >> 6;             // wave within block

    __shared__ float4 lds[4][64 * 7];              // 28672 B, per-wave private
    __shared__ float stx[2][15];                   // cross-wave combine

    const float4* g4 = reinterpret_cast<const float4*>(in) + (size_t)b * (S_LEN * 6 / 4);

    // staging maps: instr m (0..5) fills slot s=m*64+lane; rec=s/6, j=s%6.
    // global idx = (half*64+rec)*24 + round*6 + j ; LDS offset = rec*7 + j.
    int goff[6], loff[6];
    #pragma unroll
    for (int m = 0; m < 6; ++m) {
        const int s   = m * 64 + lane;
        const int rec = s / 6;
        const int j   = s - 6 * rec;
        goff[m] = (half * 64 + rec) * 24 + j;
        loff[m] = rec * 7 + j;
    }
    float4* L = &lds[wv][0];
    const int rbase = lane * 7;

    // prologue: stage round 0, then issue round-1 loads
    float4 v[6];
    #pragma unroll
    for (int m = 0; m < 6; ++m) v[m] = g4[goff[m]];
    #pragma unroll
    for (int m = 0; m < 6; ++m) L[loff[m]] = v[m];     // waits vmcnt per reg
    #pragma unroll
    for (int m = 0; m < 6; ++m) v[m] = g4[goff[m] + 6];
    asm volatile("s_waitcnt lgkmcnt(0)" ::: "memory"); // round-0 writes visible
    __builtin_amdgcn_sched_barrier(0);

    float R00 = 1.f, R01 = 0.f, R02 = 0.f;
    float R10 = 0.f, R11 = 1.f, R12 = 0.f;
    float R20 = 0.f, R21 = 0.f, R22 = 1.f;
    float Vx = 0.f, Vy = 0.f, Vz = 0.f;
    float Px = 0.f, Py = 0.f, Pz = 0.f;

    #pragma unroll 1
    for (int r = 0; r < 4; ++r) {
        // consume round r: 6 float4 = 4 steps
        const float4 q0 = L[rbase],     q1 = L[rbase + 1], q2 = L[rbase + 2];
        const float4 q3 = L[rbase + 3], q4 = L[rbase + 4], q5 = L[rbase + 5];
        istep(R00,R01,R02,R10,R11,R12,R20,R21,R22,Vx,Vy,Vz,Px,Py,Pz,
              q0.x, q0.y, q0.z, q0.w, q1.x, q1.y);
        istep(R00,R01,R02,R10,R11,R12,R20,R21,R22,Vx,Vy,Vz,Px,Py,Pz,
              q1.z, q1.w, q2.x, q2.y, q2.z, q2.w);
        istep(R00,R01,R02,R10,R11,R12,R20,R21,R22,Vx,Vy,Vz,Px,Py,Pz,
              q3.x, q3.y, q3.z, q3.w, q4.x, q4.y);
        istep(R00,R01,R02,R10,R11,R12,R20,R21,R22,Vx,Vy,Vz,Px,Py,Pz,
              q4.z, q4.w, q5.x, q5.y, q5.z, q5.w);

        if (r < 3) {
            asm volatile("s_waitcnt lgkmcnt(0)" ::: "memory"); // reads drained
            __builtin_amdgcn_sched_barrier(0);
            #pragma unroll
            for (int m = 0; m < 6; ++m) L[loff[m]] = v[m];     // round r+1
            if (r < 2) {
                #pragma unroll
                for (int m = 0; m < 6; ++m) v[m] = g4[goff[m] + (r + 2) * 6];
            }
            asm volatile("s_waitcnt lgkmcnt(0)" ::: "memory"); // writes visible
            __builtin_amdgcn_sched_barrier(0);
        }
    }

    // ordered tree reduction across the wave: lane i holds chunks [i, i+o)
    #pragma unroll
    for (int o = 1; o < 64; o <<= 1) {
        const float Tb = (float)(o * CHUNK) * DT;
        const float S00 = __shfl_down(R00, o, 64), S01 = __shfl_down(R01, o, 64), S02 = __shfl_down(R02, o, 64);
        const float S10 = __shfl_down(R10, o, 64), S11 = __shfl_down(R11, o, 64), S12 = __shfl_down(R12, o, 64);
        const float S20 = __shfl_down(R20, o, 64), S21 = __shfl_down(R21, o, 64), S22 = __shfl_down(R22, o, 64);
        const float Wx  = __shfl_down(Vx, o, 64),  Wy  = __shfl_down(Vy, o, 64),  Wz  = __shfl_down(Vz, o, 64);
        const float Qx  = __shfl_down(Px, o, 64),  Qy  = __shfl_down(Py, o, 64),  Qz  = __shfl_down(Pz, o, 64);

        const float nPx = Px + Vx * Tb + R00 * Qx + R01 * Qy + R02 * Qz;
        const float nPy = Py + Vy * Tb + R10 * Qx + R11 * Qy + R12 * Qz;
        const float nPz = Pz + Vz * Tb + R20 * Qx + R21 * Qy + R22 * Qz;
        const float nVx = Vx + R00 * Wx + R01 * Wy + R02 * Wz;
        const float nVy = Vy + R10 * Wx + R11 * Wy + R12 * Wz;
        const float nVz = Vz + R20 * Wx + R21 * Wy + R22 * Wz;
        float r0, r1, r2;
        r0 = R00 * S00 + R01 * S10 + R02 * S20;
        r1 = R00 * S01 + R01 * S11 + R02 * S21;
        r2 = R00 * S02 + R01 * S12 + R02 * S22;
        R00 = r0; R01 = r1; R02 = r2;
        r0 = R10 * S00 + R11 * S10 + R12 * S20;
        r1 = R10 * S01 + R11 * S11 + R12 * S21;
        r2 = R10 * S02 + R11 * S12 + R12 * S22;
        R10 = r0; R11 = r1; R12 = r2;
        r0 = R20 * S00 + R21 * S10 + R22 * S20;
        r1 = R20 * S01 + R21 * S11 + R22 * S21;
        r2 = R20 * S02 + R21 * S12 + R22 * S22;
        R20 = r0; R21 = r1; R22 = r2;

        Px = nPx; Py = nPy; Pz = nPz;
        Vx = nVx; Vy = nVy; Vz = nVz;
    }

    // cross-wave combine: wave 1 of each batch parks its state in LDS
    if (lane == 0 && half == 1) {
        float* s = stx[slot];
        s[0]=R00; s[1]=R01; s[2]=R02; s[3]=R10; s[4]=R11; s[5]=R12;
        s[6]=R20; s[7]=R21; s[8]=R22; s[9]=Vx; s[10]=Vy; s[11]=Vz;
        s[12]=Px; s[13]=Py; s[14]=Pz;
    }
    __syncthreads();

    if (tid == 0) {
        const float* s = stx[slot];
        const float S00=s[0],S01=s[1],S02=s[2],S10=s[3],S11=s[4],S12=s[5];
        const float S20=s[6],S21=s[7],S22=s[8],Wx=s[9],Wy=s[10],Wz=s[11];
        const float Qx=s[12],Qy=s[13],Qz=s[14];
        const float Tb = (float)(64 * CHUNK) * DT;

        const float nPx = Px + Vx * Tb + R00 * Qx + R01 * Qy + R02 * Qz;
        const float nPy = Py + Vy * Tb + R10 * Qx + R11 * Qy + R12 * Qz;
        const float nPz = Pz + Vz * Tb + R20 * Qx + R21 * Qy + R22 * Qz;
        float r0, r1, r2;
        r0 = R00 * S00 + R01 * S10 + R02 * S20;
        r1 = R00 * S01 + R01 * S11 + R02 * S21;
        r2 = R00 * S02 + R01 * S12 + R02 * S22;
        const float F00 = r0, F01 = r1, F02 = r2;
        r0 = R10 * S00 + R11 * S10 + R12 * S20;
        r1 = R10 * S01 + R11 * S11 + R12 * S21;
        r2 = R10 * S02 + R11 * S12 + R12 * S22;
        const float F10 = r0, F11 = r1, F12 = r2;
        r0 = R20 * S00 + R21 * S10 + R22 * S20;
        r1 = R20 * S01 + R21 * S11 + R22 * S21;
        r2 = R20 * S02 + R21 * S12 + R22 * S22;
        const float F20 = r0, F21 = r1, F22 = r2;

        const float tr = F00 + F11 + F22;
        float c = (tr - 1.0f) * 0.5f;
        c = fminf(fmaxf(c, -1.0f + 1e-7f), 1.0f - 1e-7f);
        const float angle = acosf(c);
        const float sden = fmaxf(2.0f * sinf(angle), 1e-12f);
        const float axx = (F21 - F12) / sden;
        const float ayy = (F02 - F20) / sden;
        const float azz = (F10 - F01) / sden;
        const float halfang = angle * 0.5f;
        const float sh = sinf(halfang), ch = cosf(halfang);
        float* o = out + (size_t)b * 7;
        o[0] = nPx; o[1] = nPy; o[2] = nPz;
        o[3] = ch;
        o[4] = axx * sh; o[5] = ayy * sh; o[6] = azz * sh;
    }
}

extern "C" void kernel_launch(void* const* d_in, const int* in_sizes, int n_in,
                              void* d_out, int out_size, void* d_ws, size_t ws_size,
                              hipStream_t stream)
{
    const float* in = (const float*)d_in[0];
    float* out = (float*)d_out;
    const int threads = 256;
    const int blocks = B_TOT / 2;   // 2048 blocks, 2 batches per block
    preint_kernel<<<blocks, threads, 0, stream>>>(in, out);
}

// Round 11
// 81.811 us; speedup vs baseline: 1.1091x; 1.1091x over previous
//
#include <hip/hip_runtime.h>
#include <math.h>

#define S_LEN 2048
#define B_TOT 4096
#define CHUNK 32                  // steps per lane; 1 wave (64 lanes) per batch
constexpr float DT       = 1.0f / 200.0f;
constexpr float HALF_DT2 = DT * DT * 0.5f;

// One preintegration step applied to running segment state (R,V,P).
__device__ __forceinline__ void istep(
    float& R00, float& R01, float& R02,
    float& R10, float& R11, float& R12,
    float& R20, float& R21, float& R22,
    float& Vx, float& Vy, float& Vz,
    float& Px, float& Py, float& Pz,
    float wx, float wy, float wz, float ax, float ay, float az)
{
    const float ux = wx * DT, uy = wy * DT, uz = wz * DT;
    const float t2 = ux * ux + uy * uy + uz * uz;          // theta^2 (tiny)
    const float Ac = 1.0f + t2 * (-1.0f / 6.0f  + t2 * (1.0f / 120.0f));
    const float Bc = 0.5f + t2 * (-1.0f / 24.0f + t2 * (1.0f / 720.0f));

    const float K00 = 1.0f + Bc * (ux * ux - t2);
    const float K11 = 1.0f + Bc * (uy * uy - t2);
    const float K22 = 1.0f + Bc * (uz * uz - t2);
    const float bxy = Bc * ux * uy, bxz = Bc * ux * uz, byz = Bc * uy * uz;
    const float aux = Ac * ux, auy = Ac * uy, auz = Ac * uz;
    const float K01 = bxy - auz, K10 = bxy + auz;
    const float K02 = bxz + auy, K20 = bxz - auy;
    const float K12 = byz - aux, K21 = byz + aux;

    float r0, r1, r2;
    r0 = R00 * K00 + R01 * K10 + R02 * K20;
    r1 = R00 * K01 + R01 * K11 + R02 * K21;
    r2 = R00 * K02 + R01 * K12 + R02 * K22;
    R00 = r0; R01 = r1; R02 = r2;
    r0 = R10 * K00 + R11 * K10 + R12 * K20;
    r1 = R10 * K01 + R11 * K11 + R12 * K21;
    r2 = R10 * K02 + R11 * K12 + R12 * K22;
    R10 = r0; R11 = r1; R12 = r2;
    r0 = R20 * K00 + R21 * K10 + R22 * K20;
    r1 = R20 * K01 + R21 * K11 + R22 * K21;
    r2 = R20 * K02 + R21 * K12 + R22 * K22;
    R20 = r0; R21 = r1; R22 = r2;

    const float tx = R00 * ax + R01 * ay + R02 * az;
    const float ty = R10 * ax + R11 * ay + R12 * az;
    const float tz = R20 * ax + R21 * ay + R22 * az;
    Vx += tx * DT; Vy += ty * DT; Vz += tz * DT;
    Px += Vx * DT + tx * HALF_DT2;
    Py += Vy * DT + ty * HALF_DT2;
    Pz += Vz * DT + tz * HALF_DT2;
}

// block = 256 = 4 waves = 4 batches (1 wave/batch); 1024 blocks.
// R9's proven envelope (53KB LDS -> 3 blocks/CU so the allocator keeps a
// generous VGPR budget and never spills; (256,2); fully straight-line body;
// fences at every LDS write<->read transition) with CHUNK=32: 4 rounds of
// 12 float4/lane instead of 2 -> loads in flight during 3 of 4 consume
// rounds (75% duty vs R9's 50%). Same coalesced staging: instr m loads
// slot m*64+lane -> (rec=s/12, j=s%12), 192B contiguous per record. LDS
// record stride 13 float4 (odd) -> conflict-free b128 reads.
__global__ __launch_bounds__(256, 2)
void preint_kernel(const float* __restrict__ in, float* __restrict__ out)
{
    const int wv   = threadIdx.x >> 6;             // wave in block = batch slot
    const int b    = blockIdx.x * 4 + wv;
    const int lane = threadIdx.x & 63;

    __shared__ float4 lds[4][64 * 13];             // 53248 B, per-wave private

    const float4* g4 = reinterpret_cast<const float4*>(in) + (size_t)b * (S_LEN * 6 / 4);

    // staging maps: instr m (0..11) fills slot s=m*64+lane; rec=s/12, j=s%12.
    // record = 32 steps = 48 float4; global idx = rec*48 + round*12 + j.
    int goff[12], loff[12];
    #pragma unroll
    for (int m = 0; m < 12; ++m) {
        const int s   = m * 64 + lane;
        const int rec = s / 12;
        const int j   = s - 12 * rec;
        goff[m] = rec * 48 + j;
        loff[m] = rec * 13 + j;
    }
    float4* L = &lds[wv][0];
    const int rbase = lane * 13;

    // prologue: stage round 0, then issue round-1 loads
    float4 v[12];
    #pragma unroll
    for (int m = 0; m < 12; ++m) v[m] = g4[goff[m]];
    #pragma unroll
    for (int m = 0; m < 12; ++m) L[loff[m]] = v[m];     // waits vmcnt per reg
    #pragma unroll
    for (int m = 0; m < 12; ++m) v[m] = g4[goff[m] + 12];
    asm volatile("s_waitcnt lgkmcnt(0)" ::: "memory");  // round-0 writes visible
    __builtin_amdgcn_sched_barrier(0);

    float R00 = 1.f, R01 = 0.f, R02 = 0.f;
    float R10 = 0.f, R11 = 1.f, R12 = 0.f;
    float R20 = 0.f, R21 = 0.f, R22 = 1.f;
    float Vx = 0.f, Vy = 0.f, Vz = 0.f;
    float Px = 0.f, Py = 0.f, Pz = 0.f;

    // 4 rounds, fully unrolled (straight-line like R9 — rolled loop invited
    // the R10 spill). Round r consumes 12 float4 = 8 steps while round r+1's
    // loads are in flight; rounds r+2 issued right after r+1's LDS write.
    #pragma unroll
    for (int r = 0; r < 4; ++r) {
        #pragma unroll
        for (int t = 0; t < 4; ++t) {
            const float4 q0 = L[rbase + 3 * t];
            const float4 q1 = L[rbase + 3 * t + 1];
            const float4 q2 = L[rbase + 3 * t + 2];
            istep(R00,R01,R02,R10,R11,R12,R20,R21,R22,Vx,Vy,Vz,Px,Py,Pz,
                  q0.x, q0.y, q0.z, q0.w, q1.x, q1.y);
            istep(R00,R01,R02,R10,R11,R12,R20,R21,R22,Vx,Vy,Vz,Px,Py,Pz,
                  q1.z, q1.w, q2.x, q2.y, q2.z, q2.w);
        }
        if (r < 3) {
            asm volatile("s_waitcnt lgkmcnt(0)" ::: "memory"); // reads drained
            __builtin_amdgcn_sched_barrier(0);
            #pragma unroll
            for (int m = 0; m < 12; ++m) L[loff[m]] = v[m];    // round r+1
            if (r < 2) {
                #pragma unroll
                for (int m = 0; m < 12; ++m) v[m] = g4[goff[m] + (r + 2) * 12];
            }
            asm volatile("s_waitcnt lgkmcnt(0)" ::: "memory"); // writes visible
            __builtin_amdgcn_sched_barrier(0);
        }
    }

    // ordered tree reduction across the wave: lane i holds chunks [i, i+o)
    #pragma unroll
    for (int o = 1; o < 64; o <<= 1) {
        const float Tb = (float)(o * CHUNK) * DT;
        const float S00 = __shfl_down(R00, o, 64), S01 = __shfl_down(R01, o, 64), S02 = __shfl_down(R02, o, 64);
        const float S10 = __shfl_down(R10, o, 64), S11 = __shfl_down(R11, o, 64), S12 = __shfl_down(R12, o, 64);
        const float S20 = __shfl_down(R20, o, 64), S21 = __shfl_down(R21, o, 64), S22 = __shfl_down(R22, o, 64);
        const float Wx  = __shfl_down(Vx, o, 64),  Wy  = __shfl_down(Vy, o, 64),  Wz  = __shfl_down(Vz, o, 64);
        const float Qx  = __shfl_down(Px, o, 64),  Qy  = __shfl_down(Py, o, 64),  Qz  = __shfl_down(Pz, o, 64);

        const float nPx = Px + Vx * Tb + R00 * Qx + R01 * Qy + R02 * Qz;
        const float nPy = Py + Vy * Tb + R10 * Qx + R11 * Qy + R12 * Qz;
        const float nPz = Pz + Vz * Tb + R20 * Qx + R21 * Qy + R22 * Qz;
        const float nVx = Vx + R00 * Wx + R01 * Wy + R02 * Wz;
        const float nVy = Vy + R10 * Wx + R11 * Wy + R12 * Wz;
        const float nVz = Vz + R20 * Wx + R21 * Wy + R22 * Wz;
        float r0, r1, r2;
        r0 = R00 * S00 + R01 * S10 + R02 * S20;
        r1 = R00 * S01 + R01 * S11 + R02 * S21;
        r2 = R00 * S02 + R01 * S12 + R02 * S22;
        R00 = r0; R01 = r1; R02 = r2;
        r0 = R10 * S00 + R11 * S10 + R12 * S20;
        r1 = R10 * S01 + R11 * S11 + R12 * S21;
        r2 = R10 * S02 + R11 * S12 + R12 * S22;
        R10 = r0; R11 = r1; R12 = r2;
        r0 = R20 * S00 + R21 * S10 + R22 * S20;
        r1 = R20 * S01 + R21 * S11 + R22 * S21;
        r2 = R20 * S02 + R21 * S12 + R22 * S22;
        R20 = r0; R21 = r1; R22 = r2;

        Px = nPx; Py = nPy; Pz = nPz;
        Vx = nVx; Vy = nVy; Vz = nVz;
    }

    if (lane == 0) {
        const float tr = R00 + R11 + R22;
        float c = (tr - 1.0f) * 0.5f;
        c = fminf(fmaxf(c, -1.0f + 1e-7f), 1.0f - 1e-7f);
        const float angle = acosf(c);
        const float s = fmaxf(2.0f * sinf(angle), 1e-12f);
        const float axx = (R21 - R12) / s;
        const float ayy = (R02 - R20) / s;
        const float azz = (R10 - R01) / s;
        const float half = angle * 0.5f;
        const float sh = sinf(half), ch = cosf(half);
        float* o = out + (size_t)b * 7;
        o[0] = Px; o[1] = Py; o[2] = Pz;
        o[3] = ch;
        o[4] = axx * sh; o[5] = ayy * sh; o[6] = azz * sh;
    }
}

extern "C" void kernel_launch(void* const* d_in, const int* in_sizes, int n_in,
                              void* d_out, int out_size, void* d_ws, size_t ws_size,
                              hipStream_t stream)
{
    const float* in = (const float*)d_in[0];
    float* out = (float*)d_out;
    const int threads = 256;
    const int blocks = B_TOT / 4;   // 1024 blocks, 4 batches (waves) per block
    preint_kernel<<<blocks, threads, 0, stream>>>(in, out);
}

// Round 12
// 46.426 us; speedup vs baseline: 1.9545x; 1.7622x over previous
//
#include <hip/hip_runtime.h>
#include <math.h>

#define S_LEN 2048
#define B_TOT 4096
#define CHUNK 16                  // steps per thread; 128 threads (2 waves) per batch
constexpr float DT       = 1.0f / 200.0f;
constexpr float HALF_DT2 = DT * DT * 0.5f;

// One preintegration step applied to running segment state (R,V,P).
__device__ __forceinline__ void istep(
    float& R00, float& R01, float& R02,
    float& R10, float& R11, float& R12,
    float& R20, float& R21, float& R22,
    float& Vx, float& Vy, float& Vz,
    float& Px, float& Py, float& Pz,
    float wx, float wy, float wz, float ax, float ay, float az)
{
    const float ux = wx * DT, uy = wy * DT, uz = wz * DT;
    const float t2 = ux * ux + uy * uy + uz * uz;          // theta^2 (tiny)
    const float Ac = 1.0f + t2 * (-1.0f / 6.0f  + t2 * (1.0f / 120.0f));
    const float Bc = 0.5f + t2 * (-1.0f / 24.0f + t2 * (1.0f / 720.0f));

    const float K00 = 1.0f + Bc * (ux * ux - t2);
    const float K11 = 1.0f + Bc * (uy * uy - t2);
    const float K22 = 1.0f + Bc * (uz * uz - t2);
    const float bxy = Bc * ux * uy, bxz = Bc * ux * uz, byz = Bc * uy * uz;
    const float aux = Ac * ux, auy = Ac * uy, auz = Ac * uz;
    const float K01 = bxy - auz, K10 = bxy + auz;
    const float K02 = bxz + auy, K20 = bxz - auy;
    const float K12 = byz - aux, K21 = byz + aux;

    float r0, r1, r2;
    r0 = R00 * K00 + R01 * K10 + R02 * K20;
    r1 = R00 * K01 + R01 * K11 + R02 * K21;
    r2 = R00 * K02 + R01 * K12 + R02 * K22;
    R00 = r0; R01 = r1; R02 = r2;
    r0 = R10 * K00 + R11 * K10 + R12 * K20;
    r1 = R10 * K01 + R11 * K11 + R12 * K21;
    r2 = R10 * K02 + R11 * K12 + R12 * K22;
    R10 = r0; R11 = r1; R12 = r2;
    r0 = R20 * K00 + R21 * K10 + R22 * K20;
    r1 = R20 * K01 + R21 * K11 + R22 * K21;
    r2 = R20 * K02 + R21 * K12 + R22 * K22;
    R20 = r0; R21 = r1; R22 = r2;

    const float tx = R00 * ax + R01 * ay + R02 * az;
    const float ty = R10 * ax + R11 * ay + R12 * az;
    const float tz = R20 * ax + R21 * ay + R22 * az;
    Vx += tx * DT; Vy += ty * DT; Vz += tz * DT;
    Px += Vx * DT + tx * HALF_DT2;
    Py += Vy * DT + ty * HALF_DT2;
    Pz += Vz * DT + tz * HALF_DT2;
}

// block = 256 = 4 waves = 2 batches (2 waves/batch); 2048 blocks.
// Wave-cooperative COALESCED staging: round = 12 float4/record; instr m
// loads slot m*64+lane -> (rec=s/12, j=s%12); per-record 192B contiguous
// segments => ~16-18 lines per wave instruction (vs 64 scattered in R8).
// LDS record stride 13 float4 (52 dw, odd/4) => conflict-free b128 reads.
// Round-2 loads issue BEFORE round-1 consume (latency hidden under 8 steps).
// Fences at every LDS write<->read transition (R7 race lesson).
// (256,2) caps VGPR at 128 (empirical formula 256/N: R2/R4 (256,8)->32).
// NOTE (R10/R11 post-mortems): >2 staging rounds (smaller LDS or more
// inlined steps) trips the allocator into voluntary spill (R10: VGPR 60 +
// 139MB scratch; R11: 81.8us). 53KB LDS -> 3 blocks/CU keeps the allocator
// generous. This exact shape is the empirical optimum: 46.4us, 4.34 TB/s.
__global__ __launch_bounds__(256, 2)
void preint_kernel(const float* __restrict__ in, float* __restrict__ out)
{
    const int slot = threadIdx.x >> 7;             // batch within block (0..1)
    const int b    = blockIdx.x * 2 + slot;
    const int tid  = threadIdx.x & 127;            // thread within batch = record
    const int lane = threadIdx.x & 63;
    const int half = (threadIdx.x >> 6) & 1;       // which wave of the batch
    const int wv   = threadIdx.x >> 6;             // wave within block

    __shared__ float4 lds[4][64 * 13];             // 53248 B, per-wave private
    __shared__ float stx[2][15];                   // cross-wave combine

    const float4* g4 = reinterpret_cast<const float4*>(in) + (size_t)b * (S_LEN * 6 / 4);

    // staging maps (unrolled -> registers, all statically indexed)
    int goff[12], loff[12];
    #pragma unroll
    for (int m = 0; m < 12; ++m) {
        const int s   = m * 64 + lane;
        const int rec = s / 12;                    // magic-mul, compile-time const divisor
        const int j   = s - 12 * rec;
        goff[m] = (half * 64 + rec) * 24 + j;      // record = 24 float4; +12 for round 2
        loff[m] = rec * 13 + j;                    // padded LDS stride
    }
    float4* L = &lds[wv][0];
    const int rbase = lane * 13;

    // ---- stage round 1 (coalesced) ----
    float4 v[12];
    #pragma unroll
    for (int m = 0; m < 12; ++m) v[m] = g4[goff[m]];
    #pragma unroll
    for (int m = 0; m < 12; ++m) L[loff[m]] = v[m];    // compiler waits vmcnt per reg

    // ---- issue round 2 loads early (hide under round-1 consume) ----
    #pragma unroll
    for (int m = 0; m < 12; ++m) v[m] = g4[goff[m] + 12];

    asm volatile("s_waitcnt lgkmcnt(0)" ::: "memory"); // round-1 writes visible
    __builtin_amdgcn_sched_barrier(0);

    float R00 = 1.f, R01 = 0.f, R02 = 0.f;
    float R10 = 0.f, R11 = 1.f, R12 = 0.f;
    float R20 = 0.f, R21 = 0.f, R22 = 1.f;
    float Vx = 0.f, Vy = 0.f, Vz = 0.f;
    float Px = 0.f, Py = 0.f, Pz = 0.f;

    // ---- consume round 1: 8 steps (4 triplets) ----
    #pragma unroll
    for (int t = 0; t < 4; ++t) {
        const float4 q0 = L[rbase + 3 * t];
        const float4 q1 = L[rbase + 3 * t + 1];
        const float4 q2 = L[rbase + 3 * t + 2];
        istep(R00,R01,R02,R10,R11,R12,R20,R21,R22,Vx,Vy,Vz,Px,Py,Pz,
              q0.x, q0.y, q0.z, q0.w, q1.x, q1.y);
        istep(R00,R01,R02,R10,R11,R12,R20,R21,R22,Vx,Vy,Vz,Px,Py,Pz,
              q1.z, q1.w, q2.x, q2.y, q2.z, q2.w);
    }

    asm volatile("s_waitcnt lgkmcnt(0)" ::: "memory"); // round-1 reads drained
    __builtin_amdgcn_sched_barrier(0);

    // ---- stage round 2 into same buffer ----
    #pragma unroll
    for (int m = 0; m < 12; ++m) L[loff[m]] = v[m];

    asm volatile("s_waitcnt lgkmcnt(0)" ::: "memory"); // round-2 writes visible
    __builtin_amdgcn_sched_barrier(0);

    // ---- consume round 2 ----
    #pragma unroll
    for (int t = 0; t < 4; ++t) {
        const float4 q0 = L[rbase + 3 * t];
        const float4 q1 = L[rbase + 3 * t + 1];
        const float4 q2 = L[rbase + 3 * t + 2];
        istep(R00,R01,R02,R10,R11,R12,R20,R21,R22,Vx,Vy,Vz,Px,Py,Pz,
              q0.x, q0.y, q0.z, q0.w, q1.x, q1.y);
        istep(R00,R01,R02,R10,R11,R12,R20,R21,R22,Vx,Vy,Vz,Px,Py,Pz,
              q1.z, q1.w, q2.x, q2.y, q2.z, q2.w);
    }

    // ordered tree reduction across the wave: lane i holds chunks [i, i+o)
    #pragma unroll
    for (int o = 1; o < 64; o <<= 1) {
        const float Tb = (float)(o * CHUNK) * DT;
        const float S00 = __shfl_down(R00, o, 64), S01 = __shfl_down(R01, o, 64), S02 = __shfl_down(R02, o, 64);
        const float S10 = __shfl_down(R10, o, 64), S11 = __shfl_down(R11, o, 64), S12 = __shfl_down(R12, o, 64);
        const float S20 = __shfl_down(R20, o, 64), S21 = __shfl_down(R21, o, 64), S22 = __shfl_down(R22, o, 64);
        const float Wx  = __shfl_down(Vx, o, 64),  Wy  = __shfl_down(Vy, o, 64),  Wz  = __shfl_down(Vz, o, 64);
        const float Qx  = __shfl_down(Px, o, 64),  Qy  = __shfl_down(Py, o, 64),  Qz  = __shfl_down(Pz, o, 64);

        const float nPx = Px + Vx * Tb + R00 * Qx + R01 * Qy + R02 * Qz;
        const float nPy = Py + Vy * Tb + R10 * Qx + R11 * Qy + R12 * Qz;
        const float nPz = Pz + Vz * Tb + R20 * Qx + R21 * Qy + R22 * Qz;
        const float nVx = Vx + R00 * Wx + R01 * Wy + R02 * Wz;
        const float nVy = Vy + R10 * Wx + R11 * Wy + R12 * Wz;
        const float nVz = Vz + R20 * Wx + R21 * Wy + R22 * Wz;
        float r0, r1, r2;
        r0 = R00 * S00 + R01 * S10 + R02 * S20;
        r1 = R00 * S01 + R01 * S11 + R02 * S21;
        r2 = R00 * S02 + R01 * S12 + R02 * S22;
        R00 = r0; R01 = r1; R02 = r2;
        r0 = R10 * S00 + R11 * S10 + R12 * S20;
        r1 = R10 * S01 + R11 * S11 + R12 * S21;
        r2 = R10 * S02 + R11 * S12 + R12 * S22;
        R10 = r0; R11 = r1; R12 = r2;
        r0 = R20 * S00 + R21 * S10 + R22 * S20;
        r1 = R20 * S01 + R21 * S11 + R22 * S21;
        r2 = R20 * S02 + R21 * S12 + R22 * S22;
        R20 = r0; R21 = r1; R22 = r2;

        Px = nPx; Py = nPy; Pz = nPz;
        Vx = nVx; Vy = nVy; Vz = nVz;
    }

    // cross-wave combine: wave 1 of each batch parks its state in LDS
    if (lane == 0 && half == 1) {
        float* s = stx[slot];
        s[0]=R00; s[1]=R01; s[2]=R02; s[3]=R10; s[4]=R11; s[5]=R12;
        s[6]=R20; s[7]=R21; s[8]=R22; s[9]=Vx; s[10]=Vy; s[11]=Vz;
        s[12]=Px; s[13]=Py; s[14]=Pz;
    }
    __syncthreads();

    if (tid == 0) {
        const float* s = stx[slot];
        const float S00=s[0],S01=s[1],S02=s[2],S10=s[3],S11=s[4],S12=s[5];
        const float S20=s[6],S21=s[7],S22=s[8],Wx=s[9],Wy=s[10],Wz=s[11];
        const float Qx=s[12],Qy=s[13],Qz=s[14];
        const float Tb = (float)(64 * CHUNK) * DT;

        const float nPx = Px + Vx * Tb + R00 * Qx + R01 * Qy + R02 * Qz;
        const float nPy = Py + Vy * Tb + R10 * Qx + R11 * Qy + R12 * Qz;
        const float nPz = Pz + Vz * Tb + R20 * Qx + R21 * Qy + R22 * Qz;
        float r0, r1, r2;
        r0 = R00 * S00 + R01 * S10 + R02 * S20;
        r1 = R00 * S01 + R01 * S11 + R02 * S21;
        r2 = R00 * S02 + R01 * S12 + R02 * S22;
        const float F00 = r0, F01 = r1, F02 = r2;
        r0 = R10 * S00 + R11 * S10 + R12 * S20;
        r1 = R10 * S01 + R11 * S11 + R12 * S21;
        r2 = R10 * S02 + R11 * S12 + R12 * S22;
        const float F10 = r0, F11 = r1, F12 = r2;
        r0 = R20 * S00 + R21 * S10 + R22 * S20;
        r1 = R20 * S01 + R21 * S11 + R22 * S21;
        r2 = R20 * S02 + R21 * S12 + R22 * S22;
        const float F20 = r0, F21 = r1, F22 = r2;

        const float tr = F00 + F11 + F22;
        float c = (tr - 1.0f) * 0.5f;
        c = fminf(fmaxf(c, -1.0f + 1e-7f), 1.0f - 1e-7f);
        const float angle = acosf(c);
        const float sden = fmaxf(2.0f * sinf(angle), 1e-12f);
        const float axx = (F21 - F12) / sden;
        const float ayy = (F02 - F20) / sden;
        const float azz = (F10 - F01) / sden;
        const float halfang = angle * 0.5f;
        const float sh = sinf(halfang), ch = cosf(halfang);
        float* o = out + (size_t)b * 7;
        o[0] = nPx; o[1] = nPy; o[2] = nPz;
        o[3] = ch;
        o[4] = axx * sh; o[5] = ayy * sh; o[6] = azz * sh;
    }
}

extern "C" void kernel_launch(void* const* d_in, const int* in_sizes, int n_in,
                              void* d_out, int out_size, void* d_ws, size_t ws_size,
                              hipStream_t stream)
{
    const float* in = (const float*)d_in[0];
    float* out = (float*)d_out;
    const int threads = 256;
    const int blocks = B_TOT / 2;   // 2048 blocks, 2 batches per block
    preint_kernel<<<blocks, threads, 0, stream>>>(in, out);
}